// Round 3
// baseline (224.678 us; speedup 1.0000x reference)
//
#include <hip/hip_runtime.h>

#define NBATCH 128
#define NANCH  8732
#define NCLS   21

#define CPB     137                    // 64-anchor chunks per batch: 136*64 + 28
#define NCHUNKS (NBATCH * CPB)         // 17536
#define K_THREADS 256
#define K_BLOCKS  1792                 // 7 blocks/CU * 256 CU
#define K_WAVES   (K_BLOCKS * 4)       // 7168 waves
#define QCH (NCHUNKS / K_WAVES)        // 2 chunks per wave...
#define RCH (NCHUNKS % K_WAVES)        // ...first 3200 waves get 3

struct BatchAcc {
    float loc;       // masked smooth-L1 sum
    float sum_all;   // sum of CE over all anchors
    float sum_pos;   // sum of CE over positive anchors
    unsigned cnt;    // positive anchor count
};

// ---------------------------------------------------------------- helpers
__device__ __forceinline__ float waveReduceF(float v) {
    #pragma unroll
    for (int o = 32; o > 0; o >>= 1) v += __shfl_down(v, o, 64);
    return v;
}
__device__ __forceinline__ unsigned waveReduceU(unsigned v) {
    #pragma unroll
    for (int o = 32; o > 0; o >>= 1) v += __shfl_down(v, o, 64);
    return v;
}

__device__ __forceinline__ float con_from_row(const float* __restrict__ row, int lbl) {
    float m = row[0];
    #pragma unroll
    for (int c = 1; c < NCLS; ++c) m = fmaxf(m, row[c]);
    float s = 0.f;
    #pragma unroll
    for (int c = 0; c < NCLS; ++c) s += __expf(row[c] - m);
    return m + __logf(s) - row[lbl];
}

// ---------------------------------------------------------------- kernel 1
// Barrier-free: each WAVE owns a private LDS region (wave-synchronous LDS,
// DS ops are in-order within a wave) and loops over 2-3 contiguous chunks of
// 64 anchors. Register accumulation across chunks; shuffle-reduce + 4 atomics
// only when the batch index changes (or at the end).
__global__ __launch_bounds__(K_THREADS) void anchor_kernel(
    const float* __restrict__ loc_out,   // [B,A,4]
    const float* __restrict__ cls_out,   // [B,A,C]
    const float* __restrict__ loc_lab,   // [B,A,4]
    const int*   __restrict__ labels,    // [B,A]
    BatchAcc* __restrict__ acc)
{
    const int w    = threadIdx.x >> 6;
    const int lane = threadIdx.x & 63;
    const int gw   = blockIdx.x * 4 + w;

    __shared__ float4 stage4[4][336];            // 4 waves * 5376 B = 21504 B
    float4* __restrict__ my4 = stage4[w];
    const float* __restrict__ myrows = (const float*)my4;

    int start, nchunk;
    if (gw < RCH) { start = gw * (QCH + 1); nchunk = QCH + 1; }
    else          { start = gw * QCH + RCH; nchunk = QCH; }

    float loc_s = 0.f, all_s = 0.f, pos_s = 0.f;
    unsigned pcnt = 0;
    int curb = -1;

    auto flush = [&]() {
        float L = waveReduceF(loc_s);
        float S = waveReduceF(all_s);
        float P = waveReduceF(pos_s);
        unsigned C = waveReduceU(pcnt);
        if (lane == 0) {
            atomicAdd(&acc[curb].loc, L);
            atomicAdd(&acc[curb].sum_all, S);
            atomicAdd(&acc[curb].sum_pos, P);
            atomicAdd(&acc[curb].cnt, C);
        }
        loc_s = all_s = pos_s = 0.f; pcnt = 0;
    };

    for (int i = 0; i < nchunk; ++i) {
        const int c   = start + i;
        const int b   = c / CPB;                 // wave-uniform
        const int idx = c - b * CPB;
        const int a0  = idx << 6;
        const int cnt = (NANCH - a0 < 64) ? (NANCH - a0) : 64;   // 64 or 28
        const size_t ba0 = (size_t)b * NANCH + a0;

        if (b != curb) {
            if (curb >= 0) flush();
            curb = b;
        }

        // ---- issue all global loads for this chunk (coalesced float4)
        const int nf4 = (cnt * NCLS) >> 2;       // 336 or 147 (always %1 exact)
        const float4* __restrict__ src4 = (const float4*)(cls_out + ba0 * NCLS);
        float4 r[6];
        #pragma unroll
        for (int j = 0; j < 6; ++j) {
            int fi = j * 64 + lane;
            if (fi < nf4) r[j] = src4[fi];
        }
        const bool active = lane < cnt;
        int lbl = 0;
        float4 lo4 = {0,0,0,0}, ll4 = {0,0,0,0};
        if (active) {
            lbl = labels[ba0 + lane];
            lo4 = ((const float4*)loc_out)[ba0 + lane];
            ll4 = ((const float4*)loc_lab)[ba0 + lane];
        }

        // ---- wave-private LDS transpose (no __syncthreads: DS in-order per wave)
        #pragma unroll
        for (int j = 0; j < 6; ++j) {
            int fi = j * 64 + lane;
            if (fi < nf4) my4[fi] = r[j];
        }

        if (active) {
            float con = con_from_row(myrows + lane * NCLS, lbl);
            all_s += con;
            if (lbl > 0) {
                pos_s += con;
                pcnt++;
                float d0 = lo4.x - ll4.x, d1 = lo4.y - ll4.y,
                      d2 = lo4.z - ll4.z, d3 = lo4.w - ll4.w;
                float a0f = fabsf(d0), a1f = fabsf(d1), a2f = fabsf(d2), a3f = fabsf(d3);
                loc_s += ((a0f < 1.f) ? 0.5f * d0 * d0 : (a0f - 0.5f))
                       + ((a1f < 1.f) ? 0.5f * d1 * d1 : (a1f - 0.5f))
                       + ((a2f < 1.f) ? 0.5f * d2 * d2 : (a2f - 0.5f))
                       + ((a3f < 1.f) ? 0.5f * d3 * d3 : (a3f - 0.5f));
            }
        }
    }
    if (curb >= 0) flush();
}

// ---------------------------------------------------------------- kernel 2
__global__ __launch_bounds__(256) void finalize_kernel(
    const float* __restrict__ cls_out,
    const int*   __restrict__ labels,
    const BatchAcc* __restrict__ acc,
    float* __restrict__ out)
{
    const int b   = blockIdx.x;
    const int tid = threadIdx.x;
    BatchAcc a = acc[b];

    long long k = (long long)3 * (long long)a.cnt;
    if (k > NANCH) k = NANCH;
    if (k == 0) k = 3;

    float con_loss;

    if (k >= NANCH) {
        // hot path: neg_mask all-ones -> con_loss = sum_all + sum_pos
        con_loss = a.sum_all + a.sum_pos;
        if (tid == 0) {
            float denom = (a.cnt != 0u) ? (float)a.cnt : 1.f;
            atomicAdd(out, (a.loc + con_loss) / denom * (1.f / NBATCH));
        }
        return;
    }

    // ---------------- cold general path: exact top-k of con_neg ----------------
    __shared__ float    sF[256];
    __shared__ unsigned sU[256];
    __shared__ float    bcastF;

    auto count_gt = [&](float t) -> unsigned {
        unsigned c = 0;
        for (int an = tid; an < NANCH; an += 256) {
            size_t ba = (size_t)b * NANCH + an;
            int lbl = labels[ba];
            if (lbl > 0) continue;
            float con = con_from_row(cls_out + ba * NCLS, lbl);
            if (con > t) c++;
        }
        sU[tid] = c; __syncthreads();
        for (int o = 128; o > 0; o >>= 1) {
            if (tid < o) sU[tid] += sU[tid + o];
            __syncthreads();
        }
        unsigned r = sU[0]; __syncthreads();
        return r;
    };

    unsigned cpos = count_gt(0.0f);
    float negpart = 0.f;

    if ((unsigned long long)k <= (unsigned long long)cpos) {
        unsigned lo = 0u, hi = 0x7F800000u;
        while (hi - lo > 1u) {
            unsigned mid = lo + (hi - lo) / 2u;
            unsigned c = count_gt(__uint_as_float(mid));
            if (c >= (unsigned)k) lo = mid; else hi = mid;
        }
        float v = __uint_as_float(hi);
        float ss = 0.f; unsigned c1 = 0;
        for (int an = tid; an < NANCH; an += 256) {
            size_t ba = (size_t)b * NANCH + an;
            int lbl = labels[ba];
            if (lbl > 0) continue;
            float con = con_from_row(cls_out + ba * NCLS, lbl);
            if (con > v) { ss += con; c1++; }
        }
        sF[tid] = ss; sU[tid] = c1; __syncthreads();
        for (int o = 128; o > 0; o >>= 1) {
            if (tid < o) { sF[tid] += sF[tid + o]; sU[tid] += sU[tid + o]; }
            __syncthreads();
        }
        if (tid == 0) { bcastF = sF[0] + (float)((unsigned)k - sU[0]) * v; }
        __syncthreads();
        negpart = bcastF;
    } else {
        if (tid == 0) {
            float np = 0.f;
            unsigned m = (unsigned)k - cpos;
            for (int an = 0; an < NANCH; ++an) {
                size_t ba = (size_t)b * NANCH + an;
                int lbl = labels[ba];
                float con = con_from_row(cls_out + ba * NCLS, lbl);
                float cneg = (lbl > 0) ? 0.f : con;
                if (cneg > 0.f) np += con;
                else if (m > 0u) { np += con; m--; }
            }
            bcastF = np;
        }
        __syncthreads();
        negpart = bcastF;
    }

    con_loss = a.sum_pos + negpart;
    if (tid == 0) {
        float denom = (a.cnt != 0u) ? (float)a.cnt : 1.f;
        atomicAdd(out, (a.loc + con_loss) / denom * (1.f / NBATCH));
    }
}

// ---------------------------------------------------------------- launch
extern "C" void kernel_launch(void* const* d_in, const int* in_sizes, int n_in,
                              void* d_out, int out_size, void* d_ws, size_t ws_size,
                              hipStream_t stream) {
    const float* loc_out = (const float*)d_in[0];
    const float* cls_out = (const float*)d_in[1];
    const float* loc_lab = (const float*)d_in[2];
    const int*   labels  = (const int*)d_in[3];
    float* out = (float*)d_out;
    BatchAcc* acc = (BatchAcc*)d_ws;   // 128*16 = 2 KB of ws

    hipMemsetAsync(acc, 0, NBATCH * sizeof(BatchAcc), stream);
    hipMemsetAsync(out, 0, sizeof(float), stream);
    anchor_kernel<<<K_BLOCKS, K_THREADS, 0, stream>>>(loc_out, cls_out, loc_lab, labels, acc);
    finalize_kernel<<<NBATCH, 256, 0, stream>>>(cls_out, labels, acc, out);
}

// Round 4
// 179.173 us; speedup vs baseline: 1.2540x; 1.2540x over previous
//
#include <hip/hip_runtime.h>

#define NBATCH 128
#define NANCH  8732
#define NCLS   21
#define CHUNK  256
#define NCHUNK ((NANCH + CHUNK - 1) / CHUNK)   // 35 chunks of 256 anchors

// ws: float4 partial[NCHUNK * NBATCH]  -> 35*128*16 = 71680 bytes
// partial = { loc_sum, con_sum_all, con_sum_pos, pos_count }

// ---------------------------------------------------------------- helpers
__device__ __forceinline__ float waveReduceF(float v) {
    #pragma unroll
    for (int o = 32; o > 0; o >>= 1) v += __shfl_down(v, o, 64);
    return v;
}
__device__ __forceinline__ unsigned waveReduceU(unsigned v) {
    #pragma unroll
    for (int o = 32; o > 0; o >>= 1) v += __shfl_down(v, o, 64);
    return v;
}

// cross entropy used by the cold mining path (scalar row reads; never hot)
__device__ __forceinline__ float con_from_row(const float* __restrict__ row, int lbl) {
    float m = row[0];
    #pragma unroll
    for (int c = 1; c < NCLS; ++c) m = fmaxf(m, row[c]);
    float s = 0.f;
    #pragma unroll
    for (int c = 0; c < NCLS; ++c) s += __expf(row[c] - m);
    return m + __logf(s) - row[lbl];
}

// ---------------------------------------------------------------- kernel 1
// One block per (batch, 256-anchor chunk), one anchor per thread.
// Row loaded as 5 overlapping float4 + 1 scalar (dword-aligned): ~3x fewer
// TA cacheline-requests than 21 scalar loads. No register arrays (no spill),
// no LDS staging, single tail barrier. Plain float4 store of the partial.
__global__ __launch_bounds__(256) void anchor_kernel(
    const float*  __restrict__ loc_out,   // [B,A,4]
    const float*  __restrict__ cls_out,   // [B,A,C]
    const float*  __restrict__ loc_lab,   // [B,A,4]
    const int*    __restrict__ labels,    // [B,A]
    float4* __restrict__ partial)         // [NCHUNK][NBATCH]
{
    const int bid = blockIdx.x;
    const int b   = bid % NBATCH;
    const int c   = bid / NBATCH;
    const int tid = threadIdx.x;
    const int a   = c * CHUNK + tid;
    const bool active = a < NANCH;

    float loc_s = 0.f, all_s = 0.f, pos_s = 0.f;
    unsigned pc = 0;

    if (active) {
        const size_t ba = (size_t)b * NANCH + a;
        const float* __restrict__ row = cls_out + ba * NCLS;

        // 5 x float4 (offsets 0,4,8,12,16) + scalar (20); dword-aligned OK
        const float4 r0 = *(const float4*)(row +  0);
        const float4 r1 = *(const float4*)(row +  4);
        const float4 r2 = *(const float4*)(row +  8);
        const float4 r3 = *(const float4*)(row + 12);
        const float4 r4 = *(const float4*)(row + 16);
        const float  r5 = row[20];

        const int lbl = labels[ba];                        // coalesced
        const float4 lo4 = ((const float4*)loc_out)[ba];   // coalesced 16B
        const float4 ll4 = ((const float4*)loc_lab)[ba];

        // max of 21
        float m = r0.x;
        m = fmaxf(m, r0.y); m = fmaxf(m, r0.z); m = fmaxf(m, r0.w);
        m = fmaxf(m, r1.x); m = fmaxf(m, r1.y); m = fmaxf(m, r1.z); m = fmaxf(m, r1.w);
        m = fmaxf(m, r2.x); m = fmaxf(m, r2.y); m = fmaxf(m, r2.z); m = fmaxf(m, r2.w);
        m = fmaxf(m, r3.x); m = fmaxf(m, r3.y); m = fmaxf(m, r3.z); m = fmaxf(m, r3.w);
        m = fmaxf(m, r4.x); m = fmaxf(m, r4.y); m = fmaxf(m, r4.z); m = fmaxf(m, r4.w);
        m = fmaxf(m, r5);

        // sum exp
        float s = __expf(r0.x - m) + __expf(r0.y - m) + __expf(r0.z - m) + __expf(r0.w - m)
                + __expf(r1.x - m) + __expf(r1.y - m) + __expf(r1.z - m) + __expf(r1.w - m)
                + __expf(r2.x - m) + __expf(r2.y - m) + __expf(r2.z - m) + __expf(r2.w - m)
                + __expf(r3.x - m) + __expf(r3.y - m) + __expf(r3.z - m) + __expf(r3.w - m)
                + __expf(r4.x - m) + __expf(r4.y - m) + __expf(r4.z - m) + __expf(r4.w - m)
                + __expf(r5 - m);

        // row[lbl] via select chain (no dynamic register indexing -> no scratch)
        float tgt = r0.x;
        tgt = (lbl ==  1) ? r0.y : tgt;  tgt = (lbl ==  2) ? r0.z : tgt;
        tgt = (lbl ==  3) ? r0.w : tgt;  tgt = (lbl ==  4) ? r1.x : tgt;
        tgt = (lbl ==  5) ? r1.y : tgt;  tgt = (lbl ==  6) ? r1.z : tgt;
        tgt = (lbl ==  7) ? r1.w : tgt;  tgt = (lbl ==  8) ? r2.x : tgt;
        tgt = (lbl ==  9) ? r2.y : tgt;  tgt = (lbl == 10) ? r2.z : tgt;
        tgt = (lbl == 11) ? r2.w : tgt;  tgt = (lbl == 12) ? r3.x : tgt;
        tgt = (lbl == 13) ? r3.y : tgt;  tgt = (lbl == 14) ? r3.z : tgt;
        tgt = (lbl == 15) ? r3.w : tgt;  tgt = (lbl == 16) ? r4.x : tgt;
        tgt = (lbl == 17) ? r4.y : tgt;  tgt = (lbl == 18) ? r4.z : tgt;
        tgt = (lbl == 19) ? r4.w : tgt;  tgt = (lbl == 20) ? r5   : tgt;

        const float con = m + __logf(s) - tgt;
        all_s = con;
        if (lbl > 0) {
            pos_s = con;
            pc = 1;
            float d0 = lo4.x - ll4.x, d1 = lo4.y - ll4.y,
                  d2 = lo4.z - ll4.z, d3 = lo4.w - ll4.w;
            float a0 = fabsf(d0), a1 = fabsf(d1), a2 = fabsf(d2), a3 = fabsf(d3);
            loc_s = ((a0 < 1.f) ? 0.5f * d0 * d0 : (a0 - 0.5f))
                  + ((a1 < 1.f) ? 0.5f * d1 * d1 : (a1 - 0.5f))
                  + ((a2 < 1.f) ? 0.5f * d2 * d2 : (a2 - 0.5f))
                  + ((a3 < 1.f) ? 0.5f * d3 * d3 : (a3 - 0.5f));
        }
    }

    // block reduce: wave shuffle then tiny LDS
    loc_s = waveReduceF(loc_s);
    all_s = waveReduceF(all_s);
    pos_s = waveReduceF(pos_s);
    pc    = waveReduceU(pc);

    __shared__ float sL[4], sA[4], sP[4];
    __shared__ unsigned sC[4];
    const int w = tid >> 6, lane = tid & 63;
    if (lane == 0) { sL[w] = loc_s; sA[w] = all_s; sP[w] = pos_s; sC[w] = pc; }
    __syncthreads();
    if (tid == 0) {
        float L = sL[0] + sL[1] + sL[2] + sL[3];
        float S = sA[0] + sA[1] + sA[2] + sA[3];
        float P = sP[0] + sP[1] + sP[2] + sP[3];
        unsigned C = sC[0] + sC[1] + sC[2] + sC[3];
        partial[c * NBATCH + b] = make_float4(L, S, P, (float)C);
    }
}

// ---------------------------------------------------------------- kernel 2
// Single block. Threads 0..127 each own a batch: reduce the 35 partials
// (coalesced 128-wide float4 reads), apply mining formula, block-reduce mean.
__global__ __launch_bounds__(256) void finalize_kernel(
    const float* __restrict__ cls_out,
    const int*   __restrict__ labels,
    const float4* __restrict__ partial,
    float* __restrict__ out)
{
    const int tid = threadIdx.x;

    __shared__ float sLoc[NBATCH], sPos[NBATCH], sCnt[NBATCH], sConl[NBATCH];
    __shared__ unsigned sK[NBATCH];
    __shared__ unsigned nflag;
    if (tid == 0) nflag = 0;
    __syncthreads();

    if (tid < NBATCH) {
        float loc = 0.f, all = 0.f, pos = 0.f, cnt = 0.f;
        for (int c = 0; c < NCHUNK; ++c) {
            float4 p = partial[c * NBATCH + tid];
            loc += p.x; all += p.y; pos += p.z; cnt += p.w;
        }
        unsigned k = 3u * (unsigned)cnt;
        if (k > NANCH) k = NANCH;
        if (k == 0u) k = 3u;
        sLoc[tid] = loc; sPos[tid] = pos; sCnt[tid] = cnt;
        sConl[tid] = all + pos;          // hot path: neg_mask all-ones
        if (k < NANCH) { sK[tid] = k; atomicAdd(&nflag, 1u); }
        else sK[tid] = 0u;
    }
    __syncthreads();

    if (nflag) {
        // cold general path: exact top-k of con_neg, one flagged batch at a time
        __shared__ float    rF[256];
        __shared__ unsigned rU[256];
        for (int b2 = 0; b2 < NBATCH; ++b2) {
            unsigned k = sK[b2];
            if (!k) continue;

            auto count_gt = [&](float t) -> unsigned {
                unsigned cc = 0;
                for (int an = tid; an < NANCH; an += 256) {
                    size_t ba = (size_t)b2 * NANCH + an;
                    int lbl = labels[ba];
                    if (lbl > 0) continue;
                    float con = con_from_row(cls_out + ba * NCLS, lbl);
                    if (con > t) cc++;
                }
                rU[tid] = cc; __syncthreads();
                for (int o = 128; o > 0; o >>= 1) {
                    if (tid < o) rU[tid] += rU[tid + o];
                    __syncthreads();
                }
                unsigned r = rU[0]; __syncthreads();
                return r;
            };

            unsigned cpos = count_gt(0.0f);
            float negpart = 0.f;

            if (k <= cpos) {
                unsigned lo = 0u, hi = 0x7F800000u;
                while (hi - lo > 1u) {
                    unsigned mid = lo + (hi - lo) / 2u;
                    unsigned cc = count_gt(__uint_as_float(mid));
                    if (cc >= k) lo = mid; else hi = mid;
                }
                float v = __uint_as_float(hi);   // k-th largest value
                float ss = 0.f; unsigned c1 = 0;
                for (int an = tid; an < NANCH; an += 256) {
                    size_t ba = (size_t)b2 * NANCH + an;
                    int lbl = labels[ba];
                    if (lbl > 0) continue;
                    float con = con_from_row(cls_out + ba * NCLS, lbl);
                    if (con > v) { ss += con; c1++; }
                }
                rF[tid] = ss; rU[tid] = c1; __syncthreads();
                for (int o = 128; o > 0; o >>= 1) {
                    if (tid < o) { rF[tid] += rF[tid + o]; rU[tid] += rU[tid + o]; }
                    __syncthreads();
                }
                negpart = rF[0] + (float)(k - rU[0]) * v;
                __syncthreads();
            } else {
                // all strictly-positive negatives + first (k-cpos) zero-tied entries
                if (tid == 0) {
                    float np = 0.f;
                    unsigned mrem = k - cpos;
                    for (int an = 0; an < NANCH; ++an) {
                        size_t ba = (size_t)b2 * NANCH + an;
                        int lbl = labels[ba];
                        float con = con_from_row(cls_out + ba * NCLS, lbl);
                        float cneg = (lbl > 0) ? 0.f : con;
                        if (cneg > 0.f) np += con;
                        else if (mrem > 0u) { np += con; mrem--; }
                    }
                    rF[0] = np;
                }
                __syncthreads();
                negpart = rF[0];
                __syncthreads();
            }

            if (tid == 0) sConl[b2] = sPos[b2] + negpart;
            __syncthreads();
        }
    }

    // final mean over batches
    float t = 0.f;
    if (tid < NBATCH) {
        float denom = (sCnt[tid] != 0.f) ? sCnt[tid] : 1.f;
        t = (sLoc[tid] + sConl[tid]) / denom;
    }
    t = waveReduceF(t);
    __shared__ float sW[4];
    const int w = tid >> 6, lane = tid & 63;
    if (lane == 0) sW[w] = t;
    __syncthreads();
    if (tid == 0) out[0] = (sW[0] + sW[1] + sW[2] + sW[3]) * (1.f / NBATCH);
}

// ---------------------------------------------------------------- launch
extern "C" void kernel_launch(void* const* d_in, const int* in_sizes, int n_in,
                              void* d_out, int out_size, void* d_ws, size_t ws_size,
                              hipStream_t stream) {
    const float* loc_out = (const float*)d_in[0];
    const float* cls_out = (const float*)d_in[1];
    const float* loc_lab = (const float*)d_in[2];
    const int*   labels  = (const int*)d_in[3];
    float* out = (float*)d_out;
    float4* partial = (float4*)d_ws;   // 35*128*16 = 71680 B of ws

    anchor_kernel<<<NBATCH * NCHUNK, 256, 0, stream>>>(loc_out, cls_out, loc_lab, labels, partial);
    finalize_kernel<<<1, 256, 0, stream>>>(cls_out, labels, partial, out);
}

// Round 5
// 177.242 us; speedup vs baseline: 1.2676x; 1.0109x over previous
//
#include <hip/hip_runtime.h>

#define NBATCH 128
#define NANCH  8732
#define NCLS   21
#define SUBS   8
#define SUBLEN 1092                    // 7*1092 + 1088 = 8732
#define ROUNDS 5                       // ceil(1092/256)

// ws: float4 partial[NBATCH * SUBS] -> 128*8*16 = 16384 bytes
// partial = { loc_sum, con_sum_all, con_sum_pos, pos_count }

// ---------------------------------------------------------------- helpers
__device__ __forceinline__ float waveReduceF(float v) {
    #pragma unroll
    for (int o = 32; o > 0; o >>= 1) v += __shfl_down(v, o, 64);
    return v;
}
__device__ __forceinline__ unsigned waveReduceU(unsigned v) {
    #pragma unroll
    for (int o = 32; o > 0; o >>= 1) v += __shfl_down(v, o, 64);
    return v;
}

// cross entropy for the cold mining path only
__device__ __forceinline__ float con_from_row(const float* __restrict__ row, int lbl) {
    float m = row[0];
    #pragma unroll
    for (int c = 1; c < NCLS; ++c) m = fmaxf(m, row[c]);
    float s = 0.f;
    #pragma unroll
    for (int c = 0; c < NCLS; ++c) s += __expf(row[c] - m);
    return m + __logf(s) - row[lbl];
}

// ---------------------------------------------------------------- kernel 1
// 1024 blocks = 128 batches x 8 contiguous sub-ranges of 1092 anchors.
// Each block streams a ~92 KB contiguous cls span in 5 rounds of 256 anchors
// (one per thread). Row = 5 overlapping float4 + 1 scalar. No LDS staging,
// no atomics; one float4 partial per block.
__global__ __launch_bounds__(256) void anchor_kernel(
    const float*  __restrict__ loc_out,   // [B,A,4]
    const float*  __restrict__ cls_out,   // [B,A,C]
    const float*  __restrict__ loc_lab,   // [B,A,4]
    const int*    __restrict__ labels,    // [B,A]
    float4* __restrict__ partial)         // [NBATCH*SUBS]
{
    const int bid  = blockIdx.x;
    const int b    = bid >> 3;
    const int sub  = bid & 7;
    const int tid  = threadIdx.x;
    const int start = sub * SUBLEN;
    const int len   = (sub == 7) ? (NANCH - 7 * SUBLEN) : SUBLEN;   // 1088 or 1092

    float loc_s = 0.f, all_s = 0.f, pos_s = 0.f;
    unsigned pc = 0;

    #pragma unroll
    for (int r = 0; r < ROUNDS; ++r) {
        const int al = r * 256 + tid;
        if (al < len) {
            const size_t ba = (size_t)b * NANCH + start + al;
            const float* __restrict__ row = cls_out + ba * NCLS;

            const float4 r0 = *(const float4*)(row +  0);
            const float4 r1 = *(const float4*)(row +  4);
            const float4 r2 = *(const float4*)(row +  8);
            const float4 r3 = *(const float4*)(row + 12);
            const float4 r4 = *(const float4*)(row + 16);
            const float  r5 = row[20];

            const int lbl = labels[ba];
            const float4 lo4 = ((const float4*)loc_out)[ba];
            const float4 ll4 = ((const float4*)loc_lab)[ba];

            float m = r0.x;
            m = fmaxf(m, r0.y); m = fmaxf(m, r0.z); m = fmaxf(m, r0.w);
            m = fmaxf(m, r1.x); m = fmaxf(m, r1.y); m = fmaxf(m, r1.z); m = fmaxf(m, r1.w);
            m = fmaxf(m, r2.x); m = fmaxf(m, r2.y); m = fmaxf(m, r2.z); m = fmaxf(m, r2.w);
            m = fmaxf(m, r3.x); m = fmaxf(m, r3.y); m = fmaxf(m, r3.z); m = fmaxf(m, r3.w);
            m = fmaxf(m, r4.x); m = fmaxf(m, r4.y); m = fmaxf(m, r4.z); m = fmaxf(m, r4.w);
            m = fmaxf(m, r5);

            float s = __expf(r0.x - m) + __expf(r0.y - m) + __expf(r0.z - m) + __expf(r0.w - m)
                    + __expf(r1.x - m) + __expf(r1.y - m) + __expf(r1.z - m) + __expf(r1.w - m)
                    + __expf(r2.x - m) + __expf(r2.y - m) + __expf(r2.z - m) + __expf(r2.w - m)
                    + __expf(r3.x - m) + __expf(r3.y - m) + __expf(r3.z - m) + __expf(r3.w - m)
                    + __expf(r4.x - m) + __expf(r4.y - m) + __expf(r4.z - m) + __expf(r4.w - m)
                    + __expf(r5 - m);

            float tgt = r0.x;
            tgt = (lbl ==  1) ? r0.y : tgt;  tgt = (lbl ==  2) ? r0.z : tgt;
            tgt = (lbl ==  3) ? r0.w : tgt;  tgt = (lbl ==  4) ? r1.x : tgt;
            tgt = (lbl ==  5) ? r1.y : tgt;  tgt = (lbl ==  6) ? r1.z : tgt;
            tgt = (lbl ==  7) ? r1.w : tgt;  tgt = (lbl ==  8) ? r2.x : tgt;
            tgt = (lbl ==  9) ? r2.y : tgt;  tgt = (lbl == 10) ? r2.z : tgt;
            tgt = (lbl == 11) ? r2.w : tgt;  tgt = (lbl == 12) ? r3.x : tgt;
            tgt = (lbl == 13) ? r3.y : tgt;  tgt = (lbl == 14) ? r3.z : tgt;
            tgt = (lbl == 15) ? r3.w : tgt;  tgt = (lbl == 16) ? r4.x : tgt;
            tgt = (lbl == 17) ? r4.y : tgt;  tgt = (lbl == 18) ? r4.z : tgt;
            tgt = (lbl == 19) ? r4.w : tgt;  tgt = (lbl == 20) ? r5   : tgt;

            const float con = m + __logf(s) - tgt;
            all_s += con;
            if (lbl > 0) {
                pos_s += con;
                pc++;
                float d0 = lo4.x - ll4.x, d1 = lo4.y - ll4.y,
                      d2 = lo4.z - ll4.z, d3 = lo4.w - ll4.w;
                float a0 = fabsf(d0), a1 = fabsf(d1), a2 = fabsf(d2), a3 = fabsf(d3);
                loc_s += ((a0 < 1.f) ? 0.5f * d0 * d0 : (a0 - 0.5f))
                       + ((a1 < 1.f) ? 0.5f * d1 * d1 : (a1 - 0.5f))
                       + ((a2 < 1.f) ? 0.5f * d2 * d2 : (a2 - 0.5f))
                       + ((a3 < 1.f) ? 0.5f * d3 * d3 : (a3 - 0.5f));
            }
        }
    }

    // block reduce: wave shuffle then tiny LDS
    loc_s = waveReduceF(loc_s);
    all_s = waveReduceF(all_s);
    pos_s = waveReduceF(pos_s);
    pc    = waveReduceU(pc);

    __shared__ float sL[4], sA[4], sP[4];
    __shared__ unsigned sC[4];
    const int w = tid >> 6, lane = tid & 63;
    if (lane == 0) { sL[w] = loc_s; sA[w] = all_s; sP[w] = pos_s; sC[w] = pc; }
    __syncthreads();
    if (tid == 0) {
        float L = sL[0] + sL[1] + sL[2] + sL[3];
        float S = sA[0] + sA[1] + sA[2] + sA[3];
        float P = sP[0] + sP[1] + sP[2] + sP[3];
        unsigned C = sC[0] + sC[1] + sC[2] + sC[3];
        partial[bid] = make_float4(L, S, P, (float)C);
    }
}

// ---------------------------------------------------------------- kernel 2
// Single block. Threads 0..127 each own a batch: reduce the 8 partials,
// apply mining formula (hot path: all-ones neg_mask), block-reduce the mean.
__global__ __launch_bounds__(256) void finalize_kernel(
    const float* __restrict__ cls_out,
    const int*   __restrict__ labels,
    const float4* __restrict__ partial,
    float* __restrict__ out)
{
    const int tid = threadIdx.x;

    __shared__ float sLoc[NBATCH], sPos[NBATCH], sCnt[NBATCH], sConl[NBATCH];
    __shared__ unsigned sK[NBATCH];
    __shared__ unsigned nflag;
    if (tid == 0) nflag = 0;
    __syncthreads();

    if (tid < NBATCH) {
        float loc = 0.f, all = 0.f, pos = 0.f, cnt = 0.f;
        #pragma unroll
        for (int c = 0; c < SUBS; ++c) {
            float4 p = partial[tid * SUBS + c];
            loc += p.x; all += p.y; pos += p.z; cnt += p.w;
        }
        unsigned k = 3u * (unsigned)cnt;
        if (k > NANCH) k = NANCH;
        if (k == 0u) k = 3u;
        sLoc[tid] = loc; sPos[tid] = pos; sCnt[tid] = cnt;
        sConl[tid] = all + pos;          // hot path: neg_mask all-ones
        if (k < NANCH) { sK[tid] = k; atomicAdd(&nflag, 1u); }
        else sK[tid] = 0u;
    }
    __syncthreads();

    if (nflag) {
        // cold general path: exact top-k of con_neg per flagged batch
        __shared__ float    rF[256];
        __shared__ unsigned rU[256];
        for (int b2 = 0; b2 < NBATCH; ++b2) {
            unsigned k = sK[b2];
            if (!k) continue;

            auto count_gt = [&](float t) -> unsigned {
                unsigned cc = 0;
                for (int an = tid; an < NANCH; an += 256) {
                    size_t ba = (size_t)b2 * NANCH + an;
                    int lbl = labels[ba];
                    if (lbl > 0) continue;
                    float con = con_from_row(cls_out + ba * NCLS, lbl);
                    if (con > t) cc++;
                }
                rU[tid] = cc; __syncthreads();
                for (int o = 128; o > 0; o >>= 1) {
                    if (tid < o) rU[tid] += rU[tid + o];
                    __syncthreads();
                }
                unsigned r = rU[0]; __syncthreads();
                return r;
            };

            unsigned cpos = count_gt(0.0f);
            float negpart = 0.f;

            if (k <= cpos) {
                unsigned lo = 0u, hi = 0x7F800000u;
                while (hi - lo > 1u) {
                    unsigned mid = lo + (hi - lo) / 2u;
                    unsigned cc = count_gt(__uint_as_float(mid));
                    if (cc >= k) lo = mid; else hi = mid;
                }
                float v = __uint_as_float(hi);   // k-th largest value
                float ss = 0.f; unsigned c1 = 0;
                for (int an = tid; an < NANCH; an += 256) {
                    size_t ba = (size_t)b2 * NANCH + an;
                    int lbl = labels[ba];
                    if (lbl > 0) continue;
                    float con = con_from_row(cls_out + ba * NCLS, lbl);
                    if (con > v) { ss += con; c1++; }
                }
                rF[tid] = ss; rU[tid] = c1; __syncthreads();
                for (int o = 128; o > 0; o >>= 1) {
                    if (tid < o) { rF[tid] += rF[tid + o]; rU[tid] += rU[tid + o]; }
                    __syncthreads();
                }
                negpart = rF[0] + (float)(k - rU[0]) * v;
                __syncthreads();
            } else {
                if (tid == 0) {
                    float np = 0.f;
                    unsigned mrem = k - cpos;
                    for (int an = 0; an < NANCH; ++an) {
                        size_t ba = (size_t)b2 * NANCH + an;
                        int lbl = labels[ba];
                        float con = con_from_row(cls_out + ba * NCLS, lbl);
                        float cneg = (lbl > 0) ? 0.f : con;
                        if (cneg > 0.f) np += con;
                        else if (mrem > 0u) { np += con; mrem--; }
                    }
                    rF[0] = np;
                }
                __syncthreads();
                negpart = rF[0];
                __syncthreads();
            }

            if (tid == 0) sConl[b2] = sPos[b2] + negpart;
            __syncthreads();
        }
    }

    // final mean over batches
    float t = 0.f;
    if (tid < NBATCH) {
        float denom = (sCnt[tid] != 0.f) ? sCnt[tid] : 1.f;
        t = (sLoc[tid] + sConl[tid]) / denom;
    }
    t = waveReduceF(t);
    __shared__ float sW[4];
    const int w = tid >> 6, lane = tid & 63;
    if (lane == 0) sW[w] = t;
    __syncthreads();
    if (tid == 0) out[0] = (sW[0] + sW[1] + sW[2] + sW[3]) * (1.f / NBATCH);
}

// ---------------------------------------------------------------- launch
extern "C" void kernel_launch(void* const* d_in, const int* in_sizes, int n_in,
                              void* d_out, int out_size, void* d_ws, size_t ws_size,
                              hipStream_t stream) {
    const float* loc_out = (const float*)d_in[0];
    const float* cls_out = (const float*)d_in[1];
    const float* loc_lab = (const float*)d_in[2];
    const int*   labels  = (const int*)d_in[3];
    float* out = (float*)d_out;
    float4* partial = (float4*)d_ws;   // 128*8*16 = 16384 B of ws

    anchor_kernel<<<NBATCH * SUBS, 256, 0, stream>>>(loc_out, cls_out, loc_lab, labels, partial);
    finalize_kernel<<<1, 256, 0, stream>>>(cls_out, labels, partial, out);
}